// Round 1
// 563.523 us; speedup vs baseline: 1.1995x; 1.1995x over previous
//
#include <hip/hip_runtime.h>

// QRNN-fo layer. Dtype model v3: inputs FP32, output FP32.
//
// Pipeline:
//   K0a: X fp32->bf16 into d_out's H region (64 MiB of the 128 MiB region;
//        consumed by GEMM, then overwritten by pass2)
//   K0b: W fp32->bf16 into ws after Y
//   K1 : bf16 MFMA GEMM Y = act(X @ W^T + b)  -> bf16 Y in ws (192 MiB)
//   K2 : scan pass1  — per-chunk affine summaries (A,B), 16 chunks of 128
//   K3 : combine     — 16-step sequential composition -> chunk entry states,
//                      writes C_last
//   K4 : scan pass2  — exact per-step recurrence from chunk entry, writes H
//
// Rationale (round 4): old single-kernel scan = 256 waves total (1/CU),
// latency-bound at ~0.9 TB/s (~355 us). Chunked two-pass scan gives 4096
// waves; extra 128 MB re-read of F,Z is paid back 5x in achieved BW.

#define S_LEN 2048
#define BATCH 16
#define DHID 1024
#define N3 3072               // 3*DHID
#define MROWS (S_LEN * BATCH) // 32768
#define XELEMS ((size_t)MROWS * DHID)   // 33,554,432
#define WELEMS ((size_t)N3 * DHID)      //  3,145,728
#define YELEMS ((size_t)MROWS * N3)     // 100,663,296

typedef __attribute__((ext_vector_type(8))) short bf16x8;
typedef __attribute__((ext_vector_type(4))) float floatx4;
typedef __attribute__((ext_vector_type(4))) unsigned short u16x4;

__device__ __forceinline__ float b2f(unsigned short u) {
  return __uint_as_float(((unsigned)u) << 16);
}
__device__ __forceinline__ unsigned short f2b(float x) {
  unsigned u = __float_as_uint(x);
  u += 0x7fffu + ((u >> 16) & 1u);   // round-to-nearest-even
  return (unsigned short)(u >> 16);
}
__device__ __forceinline__ float sigmoid_f(float x) {
  return __builtin_amdgcn_rcpf(1.0f + __expf(-x));
}
__device__ __forceinline__ float tanh_f(float x) {
  return 2.0f * __builtin_amdgcn_rcpf(1.0f + __expf(-2.0f * x)) - 1.0f;
}

__device__ __forceinline__ void load_lds16(const unsigned short* g, unsigned short* l) {
  __builtin_amdgcn_global_load_lds(
      (const __attribute__((address_space(1))) void*)g,
      (__attribute__((address_space(3))) void*)l,
      16, 0, 0);
}

// ---------------------------------------------------------------------------
// fp32 -> bf16 converter (vectorized, n multiple of 4)
// ---------------------------------------------------------------------------
__global__ __launch_bounds__(256) void cvt_f32_bf16(
    const float* __restrict__ src, unsigned short* __restrict__ dst, int n4) {
  int i = blockIdx.x * 256 + threadIdx.x;
  if (i < n4) {
    float4 v = ((const float4*)src)[i];
    u16x4 o;
    o.x = f2b(v.x); o.y = f2b(v.y); o.z = f2b(v.z); o.w = f2b(v.w);
    ((u16x4*)dst)[i] = o;
  }
}

// ---------------------------------------------------------------------------
// GEMM: Y[m][n] = act( sum_k X[m][k]*W[n][k] + b[n] ), bf16 store.
// 128x128 block tile, 4 waves (2x2), each wave 64x64 via 4x4 MFMA 16x16x32.
// BK=64, single-buffered LDS via global_load_lds width 16 (m97 structure).
// Unchanged this round (286 us, MfmaUtil 32%).
// ---------------------------------------------------------------------------
__global__ __launch_bounds__(256) void qrnn_gemm(
    const unsigned short* __restrict__ X,    // (32768,1024) bf16 (converted)
    const unsigned short* __restrict__ W,    // (3072,1024)  bf16 (converted)
    const float* __restrict__ bias,          // (3072)       fp32
    unsigned short* __restrict__ Y)          // (32768,3072) bf16 activated
{
  __shared__ __align__(16) unsigned short sA[128 * 64];
  __shared__ __align__(16) unsigned short sB[128 * 64];

  const int tid = threadIdx.x;
  const int w  = tid >> 6;     // wave 0..3
  const int l  = tid & 63;     // lane
  const int lr = l & 15;
  const int lq = l >> 4;
  const int n0B = blockIdx.x * 128;
  const int m0B = blockIdx.y * 128;
  const int wm = (w >> 1) * 64;
  const int wn = (w & 1) * 64;

  floatx4 acc[4][4] = {};

  const unsigned short* gA = X + (size_t)m0B * DHID;
  const unsigned short* gB = W + (size_t)n0B * DHID;
  const int srow = tid >> 3;           // 0..31 within 32-row chunk
  const int scol = (tid & 7) << 3;     // 0..56 step 8 shorts (16 B)

  for (int k0 = 0; k0 < DHID; k0 += 64) {
#pragma unroll
    for (int j = 0; j < 4; ++j) {
      load_lds16(gA + (size_t)(j * 32 + srow) * DHID + (k0 + scol),
                 sA + (j * 2048 + w * 512));
      load_lds16(gB + (size_t)(j * 32 + srow) * DHID + (k0 + scol),
                 sB + (j * 2048 + w * 512));
    }
    __syncthreads();

#pragma unroll
    for (int kk = 0; kk < 64; kk += 32) {
      bf16x8 af[4], bf[4];
#pragma unroll
      for (int i = 0; i < 4; ++i) {
        af[i] = *(const bf16x8*)&sA[(wm + i * 16 + lr) * 64 + kk + lq * 8];
      }
#pragma unroll
      for (int j = 0; j < 4; ++j) {
        bf[j] = *(const bf16x8*)&sB[(wn + j * 16 + lr) * 64 + kk + lq * 8];
      }
#pragma unroll
      for (int i = 0; i < 4; ++i) {
#pragma unroll
        for (int j = 0; j < 4; ++j) {
          acc[i][j] = __builtin_amdgcn_mfma_f32_16x16x32_bf16(
              af[i], bf[j], acc[i][j], 0, 0, 0);
        }
      }
    }
    __syncthreads();
  }

  // Epilogue. C/D layout: col = lane&15, row = quad*4 + reg (m89/m91).
  const int seg = n0B >> 10;   // 0:Z(tanh) 1:F(sigmoid) 2:O(sigmoid)
#pragma unroll
  for (int j = 0; j < 4; ++j) {
    const int n = n0B + wn + j * 16 + lr;
    const float bv = bias[n];
#pragma unroll
    for (int i = 0; i < 4; ++i) {
      const int mb = m0B + wm + i * 16 + lq * 4;
#pragma unroll
      for (int r = 0; r < 4; ++r) {
        float v = acc[i][j][r] + bv;
        v = (seg == 0) ? tanh_f(v) : sigmoid_f(v);
        Y[(size_t)(mb + r) * N3 + n] = f2b(v);
      }
    }
  }
}

// ---------------------------------------------------------------------------
// Chunked parallel scan. c_t = f*z + (1-f)*c is linear in c:
// over a chunk, c_out = A*c_in + B with A = prod(1-f), B via same recurrence
// from 0. P=16 chunks of L=128 -> 262144 threads (4096 waves, 16/CU) vs the
// old 256-wave latency-bound single-pass kernel.
// ---------------------------------------------------------------------------
#define U 8
#define PCH 16
#define LCH (S_LEN / PCH)          // 128
#define SUBCH (LCH / U)            // 16 sub-chunks of 8 steps
#define SSTRIDE (BATCH * N3)       // 49152
#define HSTRIDE (BATCH * DHID)     // 16384
#define NT (BATCH * DHID)          // 16384 chains

// pass1: per-(chain, chunk) affine summary (A, B). Reads F,Z only (128 MB).
__global__ __launch_bounds__(256) void qrnn_scan_pass1(
    const unsigned short* __restrict__ Y,
    float* __restrict__ Aarr,            // (PCH, NT)
    float* __restrict__ Barr)            // (PCH, NT)
{
  const int g = blockIdx.x * 256 + threadIdx.x;  // 0..262143
  const int t = g & (NT - 1);
  const int p = g >> 14;
  const int b = t >> 10;
  const int d = t & 1023;
  const unsigned short* base =
      Y + (size_t)(p * LCH) * SSTRIDE + (size_t)b * N3 + d;

  float a = 1.0f, bv = 0.0f;
  unsigned short z0[U], f0[U], z1[U], f1[U];

#define LOADZF(ch, zz, ff) { \
    const unsigned short* p_ = base + (size_t)(ch) * ((size_t)U * SSTRIDE); \
    _Pragma("unroll") \
    for (int j2 = 0; j2 < U; ++j2) { \
      zz[j2] = p_[(size_t)j2 * SSTRIDE]; \
      ff[j2] = p_[(size_t)j2 * SSTRIDE + DHID]; \
    } }

#define COMPAB(zz, ff) { \
    _Pragma("unroll") \
    for (int j2 = 0; j2 < U; ++j2) { \
      float zv = b2f(zz[j2]); \
      float fv = b2f(ff[j2]); \
      a  = fmaf(-fv, a, a);            /* a *= (1-f)            */ \
      bv = fmaf(fv, zv - bv, bv);      /* bv = f*z + (1-f)*bv   */ \
    } }

  LOADZF(0, z0, f0);
  for (int ch = 0; ch < SUBCH; ch += 2) {
    LOADZF(ch + 1, z1, f1);
    COMPAB(z0, f0);
    if (ch + 2 < SUBCH) LOADZF(ch + 2, z0, f0);
    COMPAB(z1, f1);
  }
  Aarr[g] = a;
  Barr[g] = bv;
}

// combine: sequential composition across the 16 chunk summaries per chain.
// Writes chunk entry states Cin and the final C_last.
__global__ __launch_bounds__(256) void qrnn_combine(
    const float* __restrict__ Aarr,
    const float* __restrict__ Barr,
    const float* __restrict__ h0,        // (16,1024) fp32
    float* __restrict__ Cin,             // (PCH, NT)
    float* __restrict__ out)             // C_last at S*HSTRIDE + t
{
  const int t = blockIdx.x * 256 + threadIdx.x;  // 0..16383
  float c = h0[t];
#pragma unroll
  for (int p = 0; p < PCH; ++p) {
    Cin[p * NT + t] = c;
    c = fmaf(Aarr[p * NT + t], c, Barr[p * NT + t]);
  }
  out[(size_t)S_LEN * HSTRIDE + t] = c;  // C_last fp32
}

// pass2: exact per-step recurrence within each chunk from its entry state;
// h = o * c (o pre-activated by GEMM epilogue). Reads 192 MB, writes 128 MB.
__global__ __launch_bounds__(256) void qrnn_scan_pass2(
    const unsigned short* __restrict__ Y,
    const float* __restrict__ Cin,       // (PCH, NT)
    float* __restrict__ out)             // H (2048,16,1024) fp32
{
  const int g = blockIdx.x * 256 + threadIdx.x;  // 0..262143
  const int t = g & (NT - 1);
  const int p = g >> 14;
  const int b = t >> 10;
  const int d = t & 1023;
  const unsigned short* base =
      Y + (size_t)(p * LCH) * SSTRIDE + (size_t)b * N3 + d;
  float* ho = out + (size_t)(p * LCH) * HSTRIDE + (size_t)b * DHID + d;
  float c = Cin[g];

  unsigned short z0[U], f0[U], o0[U], z1[U], f1[U], o1[U];

#define LOADCH(ch, zz, ff, oo) { \
    const unsigned short* p_ = base + (size_t)(ch) * ((size_t)U * SSTRIDE); \
    _Pragma("unroll") \
    for (int j2 = 0; j2 < U; ++j2) { \
      zz[j2] = p_[(size_t)j2 * SSTRIDE]; \
      ff[j2] = p_[(size_t)j2 * SSTRIDE + DHID]; \
      oo[j2] = p_[(size_t)j2 * SSTRIDE + 2 * DHID]; \
    } }

#define COMPCH(ch, zz, ff, oo) { \
    float* q = ho + (size_t)(ch) * ((size_t)U * HSTRIDE); \
    _Pragma("unroll") \
    for (int j2 = 0; j2 < U; ++j2) { \
      float zv = b2f(zz[j2]); \
      float fv = b2f(ff[j2]); \
      float ov = b2f(oo[j2]); \
      c = fmaf(fv, zv - c, c); \
      q[(size_t)j2 * HSTRIDE] = ov * c; \
    } }

  LOADCH(0, z0, f0, o0);
  for (int ch = 0; ch < SUBCH; ch += 2) {
    LOADCH(ch + 1, z1, f1, o1);
    COMPCH(ch, z0, f0, o0);
    if (ch + 2 < SUBCH) LOADCH(ch + 2, z0, f0, o0);
    COMPCH(ch + 1, z1, f1, o1);
  }
}

// ---------------------------------------------------------------------------
extern "C" void kernel_launch(void* const* d_in, const int* in_sizes, int n_in,
                              void* d_out, int out_size, void* d_ws, size_t ws_size,
                              hipStream_t stream) {
  const float* X    = (const float*)d_in[0]; // (2048,16,1024) fp32
  const float* h0   = (const float*)d_in[1]; // (16,1024)      fp32
  const float* W    = (const float*)d_in[2]; // (3072,1024)    fp32
  const float* bias = (const float*)d_in[3]; // (3072)         fp32
  float* out = (float*)d_out;                // fp32 H ++ C_last (128.06 MiB)

  // ws: Y bf16 (192 MiB) ++ Wbf (6 MiB). Xbf (64 MiB) parks in d_out's
  // H region (128 MiB fp32) and is consumed before pass2 rewrites it.
  // A/B/Cin (3 MB total) reuse the Wbf region: Wbf is dead after the GEMM,
  // and pass1/combine/pass2 all run after it (stream-ordered).
  unsigned short* Ybf = (unsigned short*)d_ws;
  unsigned short* Wbf = Ybf + YELEMS;
  unsigned short* Xbf = (unsigned short*)out;
  float* Aarr = (float*)Wbf;                 // (16,16384) = 1 MB
  float* Barr = Aarr + PCH * NT;             // 1 MB
  float* CinA = Barr + PCH * NT;             // 1 MB

  cvt_f32_bf16<<<(int)(XELEMS / 4 + 255) / 256, 256, 0, stream>>>(X, Xbf, (int)(XELEMS / 4));
  cvt_f32_bf16<<<(int)(WELEMS / 4 + 255) / 256, 256, 0, stream>>>(W, Wbf, (int)(WELEMS / 4));
  qrnn_gemm<<<dim3(N3 / 128, MROWS / 128), 256, 0, stream>>>(Xbf, Wbf, bias, Ybf);
  qrnn_scan_pass1<<<dim3((PCH * NT) / 256), 256, 0, stream>>>(Ybf, Aarr, Barr);
  qrnn_combine<<<dim3(NT / 256), 256, 0, stream>>>(Aarr, Barr, h0, CinA, out);
  qrnn_scan_pass2<<<dim3((PCH * NT) / 256), 256, 0, stream>>>(Ybf, CinA, out);
}

// Round 2
// 562.849 us; speedup vs baseline: 1.2010x; 1.0012x over previous
//
#include <hip/hip_runtime.h>

// QRNN-fo layer. Dtype model v3: inputs FP32, output FP32.
//
// Pipeline:
//   K0a: X fp32->bf16 into d_out's H region (64 MiB of the 128 MiB region;
//        consumed by GEMM, then overwritten by pass2)
//   K0b: W fp32->bf16 into ws after Y
//   K1 : bf16 MFMA GEMM Y = act(X @ W^T + b)  -> bf16 Y in ws (192 MiB)
//   K2 : scan pass1  — per-chunk affine summaries (A,B), 32 chunks of 64
//   K3 : combine     — 32-step sequential composition -> chunk entry states,
//                      writes C_last
//   K4 : scan pass2  — exact per-step recurrence from chunk entry, writes H
//
// Round 5: scans were 3x off BW roofline (2B/lane ushort loads, thin MLP).
// Now 4 chains/thread (ushort4 8B loads, float4 16B stores), PCH=32 to keep
// 2048 waves (8/CU). A/B/Cin (6 MB) exactly fill the dead Wbf region.

#define S_LEN 2048
#define BATCH 16
#define DHID 1024
#define N3 3072               // 3*DHID
#define MROWS (S_LEN * BATCH) // 32768
#define XELEMS ((size_t)MROWS * DHID)   // 33,554,432
#define WELEMS ((size_t)N3 * DHID)      //  3,145,728
#define YELEMS ((size_t)MROWS * N3)     // 100,663,296

typedef __attribute__((ext_vector_type(8))) short bf16x8;
typedef __attribute__((ext_vector_type(4))) float floatx4;
typedef __attribute__((ext_vector_type(4))) unsigned short u16x4;

__device__ __forceinline__ float b2f(unsigned short u) {
  return __uint_as_float(((unsigned)u) << 16);
}
__device__ __forceinline__ unsigned short f2b(float x) {
  unsigned u = __float_as_uint(x);
  u += 0x7fffu + ((u >> 16) & 1u);   // round-to-nearest-even
  return (unsigned short)(u >> 16);
}
__device__ __forceinline__ float sigmoid_f(float x) {
  return __builtin_amdgcn_rcpf(1.0f + __expf(-x));
}
__device__ __forceinline__ float tanh_f(float x) {
  return 2.0f * __builtin_amdgcn_rcpf(1.0f + __expf(-2.0f * x)) - 1.0f;
}

__device__ __forceinline__ void load_lds16(const unsigned short* g, unsigned short* l) {
  __builtin_amdgcn_global_load_lds(
      (const __attribute__((address_space(1))) void*)g,
      (__attribute__((address_space(3))) void*)l,
      16, 0, 0);
}

// ---------------------------------------------------------------------------
// fp32 -> bf16 converter (vectorized, n multiple of 4)
// ---------------------------------------------------------------------------
__global__ __launch_bounds__(256) void cvt_f32_bf16(
    const float* __restrict__ src, unsigned short* __restrict__ dst, int n4) {
  int i = blockIdx.x * 256 + threadIdx.x;
  if (i < n4) {
    float4 v = ((const float4*)src)[i];
    u16x4 o;
    o.x = f2b(v.x); o.y = f2b(v.y); o.z = f2b(v.z); o.w = f2b(v.w);
    ((u16x4*)dst)[i] = o;
  }
}

// ---------------------------------------------------------------------------
// GEMM: Y[m][n] = act( sum_k X[m][k]*W[n][k] + b[n] ), bf16 store.
// 128x128 block tile, 4 waves (2x2), each wave 64x64 via 4x4 MFMA 16x16x32.
// BK=64, single-buffered LDS via global_load_lds width 16 (m97 structure).
// Unchanged this round (291 us, MfmaUtil 32%) — next round's target.
// ---------------------------------------------------------------------------
__global__ __launch_bounds__(256) void qrnn_gemm(
    const unsigned short* __restrict__ X,    // (32768,1024) bf16 (converted)
    const unsigned short* __restrict__ W,    // (3072,1024)  bf16 (converted)
    const float* __restrict__ bias,          // (3072)       fp32
    unsigned short* __restrict__ Y)          // (32768,3072) bf16 activated
{
  __shared__ __align__(16) unsigned short sA[128 * 64];
  __shared__ __align__(16) unsigned short sB[128 * 64];

  const int tid = threadIdx.x;
  const int w  = tid >> 6;     // wave 0..3
  const int l  = tid & 63;     // lane
  const int lr = l & 15;
  const int lq = l >> 4;
  const int n0B = blockIdx.x * 128;
  const int m0B = blockIdx.y * 128;
  const int wm = (w >> 1) * 64;
  const int wn = (w & 1) * 64;

  floatx4 acc[4][4] = {};

  const unsigned short* gA = X + (size_t)m0B * DHID;
  const unsigned short* gB = W + (size_t)n0B * DHID;
  const int srow = tid >> 3;           // 0..31 within 32-row chunk
  const int scol = (tid & 7) << 3;     // 0..56 step 8 shorts (16 B)

  for (int k0 = 0; k0 < DHID; k0 += 64) {
#pragma unroll
    for (int j = 0; j < 4; ++j) {
      load_lds16(gA + (size_t)(j * 32 + srow) * DHID + (k0 + scol),
                 sA + (j * 2048 + w * 512));
      load_lds16(gB + (size_t)(j * 32 + srow) * DHID + (k0 + scol),
                 sB + (j * 2048 + w * 512));
    }
    __syncthreads();

#pragma unroll
    for (int kk = 0; kk < 64; kk += 32) {
      bf16x8 af[4], bf[4];
#pragma unroll
      for (int i = 0; i < 4; ++i) {
        af[i] = *(const bf16x8*)&sA[(wm + i * 16 + lr) * 64 + kk + lq * 8];
      }
#pragma unroll
      for (int j = 0; j < 4; ++j) {
        bf[j] = *(const bf16x8*)&sB[(wn + j * 16 + lr) * 64 + kk + lq * 8];
      }
#pragma unroll
      for (int i = 0; i < 4; ++i) {
#pragma unroll
        for (int j = 0; j < 4; ++j) {
          acc[i][j] = __builtin_amdgcn_mfma_f32_16x16x32_bf16(
              af[i], bf[j], acc[i][j], 0, 0, 0);
        }
      }
    }
    __syncthreads();
  }

  // Epilogue. C/D layout: col = lane&15, row = quad*4 + reg (m89/m91).
  const int seg = n0B >> 10;   // 0:Z(tanh) 1:F(sigmoid) 2:O(sigmoid)
#pragma unroll
  for (int j = 0; j < 4; ++j) {
    const int n = n0B + wn + j * 16 + lr;
    const float bv = bias[n];
#pragma unroll
    for (int i = 0; i < 4; ++i) {
      const int mb = m0B + wm + i * 16 + lq * 4;
#pragma unroll
      for (int r = 0; r < 4; ++r) {
        float v = acc[i][j][r] + bv;
        v = (seg == 0) ? tanh_f(v) : sigmoid_f(v);
        Y[(size_t)(mb + r) * N3 + n] = f2b(v);
      }
    }
  }
}

// ---------------------------------------------------------------------------
// Chunked parallel scan, vectorized 4 chains/thread.
// c_t = f*z + (1-f)*c is linear in c: over a chunk, c_out = A*c_in + B.
// PCH=32 chunks of LCH=64 -> 131072 threads (2048 waves, 8/CU), ushort4
// 8B/lane loads, float4 16B/lane stores.
// ---------------------------------------------------------------------------
#define U 8
#define PCH 32
#define LCH (S_LEN / PCH)          // 64
#define SUBCH (LCH / U)            // 8 sub-chunks of 8 steps
#define SSTRIDE (BATCH * N3)       // 49152
#define HSTRIDE (BATCH * DHID)     // 16384
#define NT (BATCH * DHID)          // 16384 chains
#define NT4 (NT / 4)               // 4096 thread-chains (4 d each)

// pass1: per-(chain4, chunk) affine summary (A, B). Reads F,Z only (128 MB).
__global__ __launch_bounds__(256) void qrnn_scan_pass1(
    const unsigned short* __restrict__ Y,
    float* __restrict__ Aarr,            // (PCH, NT)
    float* __restrict__ Barr)            // (PCH, NT)
{
  const int g = blockIdx.x * 256 + threadIdx.x;  // 0..131071
  const int t = g & (NT4 - 1);       // 0..4095
  const int p = g >> 12;             // chunk 0..31
  const int b = t >> 8;              // batch
  const int d = (t & 255) << 2;      // d, multiple of 4
  const unsigned short* base =
      Y + (size_t)(p * LCH) * SSTRIDE + (size_t)b * N3 + d;

  float a[4] = {1.0f, 1.0f, 1.0f, 1.0f};
  float bv[4] = {0.0f, 0.0f, 0.0f, 0.0f};
  u16x4 z0[U], f0[U], z1[U], f1[U];

#define LOADZF(ch, zz, ff) { \
    const unsigned short* p_ = base + (size_t)(ch) * ((size_t)U * SSTRIDE); \
    _Pragma("unroll") \
    for (int j2 = 0; j2 < U; ++j2) { \
      zz[j2] = *(const u16x4*)(p_ + (size_t)j2 * SSTRIDE); \
      ff[j2] = *(const u16x4*)(p_ + (size_t)j2 * SSTRIDE + DHID); \
    } }

#define COMPAB(zz, ff) { \
    _Pragma("unroll") \
    for (int j2 = 0; j2 < U; ++j2) { \
      _Pragma("unroll") \
      for (int q = 0; q < 4; ++q) { \
        float zv = b2f(zz[j2][q]); \
        float fv = b2f(ff[j2][q]); \
        a[q]  = fmaf(-fv, a[q], a[q]);        /* a *= (1-f)          */ \
        bv[q] = fmaf(fv, zv - bv[q], bv[q]);  /* bv = f*z + (1-f)*bv */ \
      } \
    } }

  LOADZF(0, z0, f0);
  for (int ch = 0; ch < SUBCH; ch += 2) {
    LOADZF(ch + 1, z1, f1);
    COMPAB(z0, f0);
    if (ch + 2 < SUBCH) LOADZF(ch + 2, z0, f0);
    COMPAB(z1, f1);
  }
  ((float4*)Aarr)[g] = make_float4(a[0], a[1], a[2], a[3]);
  ((float4*)Barr)[g] = make_float4(bv[0], bv[1], bv[2], bv[3]);
}

// combine: sequential composition across the 32 chunk summaries per chain.
// Writes chunk entry states Cin and the final C_last. ~12 MB traffic, ~3 us.
__global__ __launch_bounds__(256) void qrnn_combine(
    const float* __restrict__ Aarr,
    const float* __restrict__ Barr,
    const float* __restrict__ h0,        // (16,1024) fp32
    float* __restrict__ Cin,             // (PCH, NT)
    float* __restrict__ out)             // C_last at S*HSTRIDE + t
{
  const int t = blockIdx.x * 256 + threadIdx.x;  // 0..16383
  float c = h0[t];
#pragma unroll
  for (int p = 0; p < PCH; ++p) {
    Cin[p * NT + t] = c;
    c = fmaf(Aarr[p * NT + t], c, Barr[p * NT + t]);
  }
  out[(size_t)S_LEN * HSTRIDE + t] = c;  // C_last fp32
}

// pass2: exact per-step recurrence within each chunk from its entry state;
// h = o * c (o pre-activated by GEMM epilogue). Reads 196 MB, writes 128 MB.
__global__ __launch_bounds__(256) void qrnn_scan_pass2(
    const unsigned short* __restrict__ Y,
    const float* __restrict__ Cin,       // (PCH, NT)
    float* __restrict__ out)             // H (2048,16,1024) fp32
{
  const int g = blockIdx.x * 256 + threadIdx.x;  // 0..131071
  const int t = g & (NT4 - 1);
  const int p = g >> 12;
  const int b = t >> 8;
  const int d = (t & 255) << 2;
  const unsigned short* base =
      Y + (size_t)(p * LCH) * SSTRIDE + (size_t)b * N3 + d;
  float* ho = out + (size_t)(p * LCH) * HSTRIDE + (size_t)b * DHID + d;

  float4 cv = ((const float4*)Cin)[g];
  float c[4] = {cv.x, cv.y, cv.z, cv.w};

  u16x4 z0[U], f0[U], o0[U], z1[U], f1[U], o1[U];

#define LOADCH(ch, zz, ff, oo) { \
    const unsigned short* p_ = base + (size_t)(ch) * ((size_t)U * SSTRIDE); \
    _Pragma("unroll") \
    for (int j2 = 0; j2 < U; ++j2) { \
      zz[j2] = *(const u16x4*)(p_ + (size_t)j2 * SSTRIDE); \
      ff[j2] = *(const u16x4*)(p_ + (size_t)j2 * SSTRIDE + DHID); \
      oo[j2] = *(const u16x4*)(p_ + (size_t)j2 * SSTRIDE + 2 * DHID); \
    } }

#define COMPCH(ch, zz, ff, oo) { \
    float* q_ = ho + (size_t)(ch) * ((size_t)U * HSTRIDE); \
    _Pragma("unroll") \
    for (int j2 = 0; j2 < U; ++j2) { \
      float hv[4]; \
      _Pragma("unroll") \
      for (int q = 0; q < 4; ++q) { \
        float zv = b2f(zz[j2][q]); \
        float fv = b2f(ff[j2][q]); \
        float ov = b2f(oo[j2][q]); \
        c[q] = fmaf(fv, zv - c[q], c[q]); \
        hv[q] = ov * c[q]; \
      } \
      *(float4*)(q_ + (size_t)j2 * HSTRIDE) = \
          make_float4(hv[0], hv[1], hv[2], hv[3]); \
    } }

  LOADCH(0, z0, f0, o0);
  for (int ch = 0; ch < SUBCH; ch += 2) {
    LOADCH(ch + 1, z1, f1, o1);
    COMPCH(ch, z0, f0, o0);
    if (ch + 2 < SUBCH) LOADCH(ch + 2, z0, f0, o0);
    COMPCH(ch + 1, z1, f1, o1);
  }
}

// ---------------------------------------------------------------------------
extern "C" void kernel_launch(void* const* d_in, const int* in_sizes, int n_in,
                              void* d_out, int out_size, void* d_ws, size_t ws_size,
                              hipStream_t stream) {
  const float* X    = (const float*)d_in[0]; // (2048,16,1024) fp32
  const float* h0   = (const float*)d_in[1]; // (16,1024)      fp32
  const float* W    = (const float*)d_in[2]; // (3072,1024)    fp32
  const float* bias = (const float*)d_in[3]; // (3072)         fp32
  float* out = (float*)d_out;                // fp32 H ++ C_last (128.06 MiB)

  // ws: Y bf16 (192 MiB) ++ Wbf (6 MiB). Xbf (64 MiB) parks in d_out's
  // H region (128 MiB fp32) and is consumed before pass2 rewrites it.
  // A/B/Cin (PCH*NT*4 = 2 MB each, 6 MB total) exactly fill the Wbf region
  // (WELEMS*2 = 6,291,456 B): Wbf is dead after the GEMM, and
  // pass1/combine/pass2 all run after it (stream-ordered).
  unsigned short* Ybf = (unsigned short*)d_ws;
  unsigned short* Wbf = Ybf + YELEMS;
  unsigned short* Xbf = (unsigned short*)out;
  float* Aarr = (float*)Wbf;                 // (32,16384) = 2 MB
  float* Barr = Aarr + PCH * NT;             // 2 MB
  float* CinA = Barr + PCH * NT;             // 2 MB
  static_assert((size_t)3 * PCH * NT * 4 <= (size_t)WELEMS * 2,
                "A/B/Cin must fit in Wbf region");

  cvt_f32_bf16<<<(int)(XELEMS / 4 + 255) / 256, 256, 0, stream>>>(X, Xbf, (int)(XELEMS / 4));
  cvt_f32_bf16<<<(int)(WELEMS / 4 + 255) / 256, 256, 0, stream>>>(W, Wbf, (int)(WELEMS / 4));
  qrnn_gemm<<<dim3(N3 / 128, MROWS / 128), 256, 0, stream>>>(Xbf, Wbf, bias, Ybf);
  qrnn_scan_pass1<<<dim3((PCH * NT4) / 256), 256, 0, stream>>>(Ybf, Aarr, Barr);
  qrnn_combine<<<dim3(NT / 256), 256, 0, stream>>>(Aarr, Barr, h0, CinA, out);
  qrnn_scan_pass2<<<dim3((PCH * NT4) / 256), 256, 0, stream>>>(Ybf, CinA, out);
}

// Round 3
// 561.606 us; speedup vs baseline: 1.2036x; 1.0022x over previous
//
#include <hip/hip_runtime.h>

// QRNN-fo layer. Dtype model v3: inputs FP32, output FP32.
//
// Pipeline:
//   K0a: X fp32->bf16 into d_out's H region (64 MiB; consumed by GEMM)
//   K0b: W fp32->bf16 into ws after Y
//   K1 : bf16 MFMA GEMM Y = act(X @ W^T + b)  -> bf16 Y in ws (192 MiB)
//        *** round 6: 256x256 8-phase schedule (T1+T2+T3/T4+T5) ***
//   K2 : scan pass1  — per-chunk affine summaries (A,B), 64 chunks of 32
//   K3 : combine     — 64-step sequential composition -> chunk entry states
//   K4 : scan pass2  — exact per-step recurrence from chunk entry, writes H

#define S_LEN 2048
#define BATCH 16
#define DHID 1024
#define N3 3072               // 3*DHID
#define MROWS (S_LEN * BATCH) // 32768
#define XELEMS ((size_t)MROWS * DHID)   // 33,554,432
#define WELEMS ((size_t)N3 * DHID)      //  3,145,728
#define YELEMS ((size_t)MROWS * N3)     // 100,663,296

typedef __attribute__((ext_vector_type(8))) short bf16x8;
typedef __attribute__((ext_vector_type(4))) float floatx4;
typedef __attribute__((ext_vector_type(4))) unsigned short u16x4;

__device__ __forceinline__ float b2f(unsigned short u) {
  return __uint_as_float(((unsigned)u) << 16);
}
__device__ __forceinline__ unsigned short f2b(float x) {
  unsigned u = __float_as_uint(x);
  u += 0x7fffu + ((u >> 16) & 1u);   // round-to-nearest-even
  return (unsigned short)(u >> 16);
}
__device__ __forceinline__ float sigmoid_f(float x) {
  return __builtin_amdgcn_rcpf(1.0f + __expf(-x));
}
__device__ __forceinline__ float tanh_f(float x) {
  return 2.0f * __builtin_amdgcn_rcpf(1.0f + __expf(-2.0f * x)) - 1.0f;
}

__device__ __forceinline__ void load_lds16(const unsigned short* g, unsigned short* l) {
  __builtin_amdgcn_global_load_lds(
      (const __attribute__((address_space(1))) void*)g,
      (__attribute__((address_space(3))) void*)l,
      16, 0, 0);
}

// ---------------------------------------------------------------------------
// fp32 -> bf16 converter (vectorized, n multiple of 4)
// ---------------------------------------------------------------------------
__global__ __launch_bounds__(256) void cvt_f32_bf16(
    const float* __restrict__ src, unsigned short* __restrict__ dst, int n4) {
  int i = blockIdx.x * 256 + threadIdx.x;
  if (i < n4) {
    float4 v = ((const float4*)src)[i];
    u16x4 o;
    o.x = f2b(v.x); o.y = f2b(v.y); o.z = f2b(v.z); o.w = f2b(v.w);
    ((u16x4*)dst)[i] = o;
  }
}

// ---------------------------------------------------------------------------
// GEMM, 256x256 tile, BK=64, 8 waves (2M x 4N), per-wave 128x64 output.
// 8-phase schedule (2 barriers/phase), double-buffered 128 KiB LDS,
// XOR-swizzled LDS (inverse-swizzle on global source, swizzle on ds_read:
// rule #21), counted vmcnt(4) once per K-tile (never 0 mid-loop),
// s_setprio(1) around MFMA clusters, bijective XCD blockIdx swizzle.
//
// Stage placement per window t (4 phases): p1:A-h0(t+1) p2:A-h1(t+1)
// p3:B-h0(t+2) p4:B-h1(t+2). B region of live buffer fully read by end of
// p2 (b-frags held in regs for p3/p4), A region by end of p3 -> staging
// never races reads. vmcnt(4) at p4 leaves exactly the 2 B-halves of t+2
// in flight and forces tile t+1 complete.
// ---------------------------------------------------------------------------
__global__ __launch_bounds__(512, 2) void qrnn_gemm(
    const unsigned short* __restrict__ X,    // (32768,1024) bf16
    const unsigned short* __restrict__ W,    // (3072,1024)  bf16
    const float* __restrict__ bias,          // (3072)       fp32
    unsigned short* __restrict__ Y)          // (32768,3072) bf16 activated
{
  __shared__ __align__(16) unsigned short sAq[2][256 * 64];  // 64 KiB
  __shared__ __align__(16) unsigned short sBq[2][256 * 64];  // 64 KiB

  const int tid = threadIdx.x;
  const int w   = tid >> 6;          // wave 0..7
  const int l   = tid & 63;
  const int lr  = l & 15;
  const int lq  = l >> 4;
  const int wm  = (w >> 2) * 128;    // warp_m in {0,1}
  const int wn  = (w & 3) * 64;      // warp_n in {0..3}
  const int wu  = w << 9;            // wave-uniform LDS offset (shorts)
  const int rr  = tid >> 3;          // staging row within 64-row issue
  const int sc  = ((tid & 7) ^ (rr & 7)) << 3;  // inverse-swizzled src col

  // bijective XCD swizzle: 1536 blocks = 8 XCDs x 192
  const int bid  = blockIdx.x;
  const int swz  = (bid & 7) * 192 + (bid >> 3);
  const int mblk = swz / 12;
  const int nblk = swz - mblk * 12;
  const int m0B  = mblk << 8;
  const int n0B  = nblk << 8;

  const unsigned short* gA = X + (size_t)m0B * DHID;
  const unsigned short* gB = W + (size_t)n0B * DHID;

  floatx4 acc[8][4] = {};

#define STAGE(gbase, sbase, kt, half) do {                                    \
    const unsigned short* _g =                                                \
        (gbase) + (size_t)((half) * 128 + rr) * DHID + (kt) * 64 + sc;        \
    unsigned short* _s = (sbase) + (half) * 8192 + wu;                        \
    load_lds16(_g, _s);                                                       \
    load_lds16(_g + (size_t)64 * DHID, _s + 4096);                            \
  } while (0)

#define LDSV(sbuf, row, kcol) \
    (*(const bf16x8*)&(sbuf)[(row) * 64 + ((kcol) ^ (((row) & 7) << 3))])

#define MFMA16(MQ, NQ, BB)                                                    \
  _Pragma("unroll") for (int i = 0; i < 4; ++i)                               \
  _Pragma("unroll") for (int j = 0; j < 2; ++j)                               \
  _Pragma("unroll") for (int ks = 0; ks < 2; ++ks)                            \
    acc[(MQ) * 4 + i][(NQ) * 2 + j] =                                         \
        __builtin_amdgcn_mfma_f32_16x16x32_bf16(                              \
            a[i][ks], BB[j][ks], acc[(MQ) * 4 + i][(NQ) * 2 + j], 0, 0, 0);

  // Prologue: tile 0 fully + B halves of tile 1; drain to tile-0-complete.
  STAGE(gA, &sAq[0][0], 0, 0);
  STAGE(gA, &sAq[0][0], 0, 1);
  STAGE(gB, &sBq[0][0], 0, 0);
  STAGE(gB, &sBq[0][0], 0, 1);
  STAGE(gB, &sBq[1][0], 1, 0);
  STAGE(gB, &sBq[1][0], 1, 1);
  asm volatile("s_waitcnt vmcnt(4)" ::: "memory");
  __builtin_amdgcn_s_barrier();

  for (int t = 0; t < 16; ++t) {
    const int cur = t & 1;
    const unsigned short* cA = &sAq[cur][0];
    const unsigned short* cB = &sBq[cur][0];
    bf16x8 a[4][2], b0[2][2], b1[2][2];

    // ---- phase 1: read A(mq0) + B(nq0); stage A-h0(t+1); MFMA (0,0)
#pragma unroll
    for (int i = 0; i < 4; ++i)
#pragma unroll
      for (int ks = 0; ks < 2; ++ks)
        a[i][ks] = LDSV(cA, wm + i * 16 + lr, ks * 32 + lq * 8);
#pragma unroll
    for (int j = 0; j < 2; ++j)
#pragma unroll
      for (int ks = 0; ks < 2; ++ks)
        b0[j][ks] = LDSV(cB, wn + j * 16 + lr, ks * 32 + lq * 8);
    if (t + 1 < 16) STAGE(gA, &sAq[cur ^ 1][0], t + 1, 0);
    __builtin_amdgcn_s_barrier();
    __builtin_amdgcn_s_setprio(1);
    MFMA16(0, 0, b0);
    __builtin_amdgcn_s_setprio(0);
    __builtin_amdgcn_s_barrier();

    // ---- phase 2: read B(nq1); stage A-h1(t+1); MFMA (0,1)
#pragma unroll
    for (int j = 0; j < 2; ++j)
#pragma unroll
      for (int ks = 0; ks < 2; ++ks)
        b1[j][ks] = LDSV(cB, wn + 32 + j * 16 + lr, ks * 32 + lq * 8);
    if (t + 1 < 16) STAGE(gA, &sAq[cur ^ 1][0], t + 1, 1);
    __builtin_amdgcn_s_barrier();
    __builtin_amdgcn_s_setprio(1);
    MFMA16(0, 1, b1);
    __builtin_amdgcn_s_setprio(0);
    __builtin_amdgcn_s_barrier();

    // ---- phase 3: read A(mq1); stage B-h0(t+2); MFMA (1,0)
#pragma unroll
    for (int i = 0; i < 4; ++i)
#pragma unroll
      for (int ks = 0; ks < 2; ++ks)
        a[i][ks] = LDSV(cA, wm + 64 + i * 16 + lr, ks * 32 + lq * 8);
    if (t + 2 < 16) STAGE(gB, &sBq[cur][0], t + 2, 0);
    __builtin_amdgcn_s_barrier();
    __builtin_amdgcn_s_setprio(1);
    MFMA16(1, 0, b0);
    __builtin_amdgcn_s_setprio(0);
    __builtin_amdgcn_s_barrier();

    // ---- phase 4: stage B-h1(t+2); MFMA (1,1); counted drain
    if (t + 2 < 16) STAGE(gB, &sBq[cur][0], t + 2, 1);
    __builtin_amdgcn_s_barrier();
    __builtin_amdgcn_s_setprio(1);
    MFMA16(1, 1, b1);
    __builtin_amdgcn_s_setprio(0);
    if (t < 14) asm volatile("s_waitcnt vmcnt(4)" ::: "memory");
    else        asm volatile("s_waitcnt vmcnt(0)" ::: "memory");
    __builtin_amdgcn_s_barrier();
  }

  // Epilogue. C/D layout: col = lane&15, row = quad*4 + reg (m89/m91).
  const int seg = n0B >> 10;   // 0:Z(tanh) 1:F(sigmoid) 2:O(sigmoid)
#pragma unroll
  for (int mq = 0; mq < 2; ++mq)
#pragma unroll
    for (int i = 0; i < 4; ++i) {
      const int mb = m0B + wm + mq * 64 + i * 16 + lq * 4;
#pragma unroll
      for (int nq = 0; nq < 2; ++nq)
#pragma unroll
        for (int j = 0; j < 2; ++j) {
          const int n = n0B + wn + nq * 32 + j * 16 + lr;
          const float bv = bias[n];
#pragma unroll
          for (int r = 0; r < 4; ++r) {
            float v = acc[mq * 4 + i][nq * 2 + j][r] + bv;
            v = (seg == 0) ? tanh_f(v) : sigmoid_f(v);
            Y[(size_t)(mb + r) * N3 + n] = f2b(v);
          }
        }
    }
#undef STAGE
#undef LDSV
#undef MFMA16
}

// ---------------------------------------------------------------------------
// Chunked parallel scan, 4 chains/thread, PCH=64 chunks of 32 steps.
// 262144 threads (4096 waves, 16/CU): 2x the in-flight load bytes of round 5
// (scans measured latency-bound: width-invariant at fixed waves*depth).
// ---------------------------------------------------------------------------
#define U 8
#define PCH 64
#define LCH (S_LEN / PCH)          // 32
#define SUBCH (LCH / U)            // 4 sub-chunks of 8 steps
#define SSTRIDE (BATCH * N3)       // 49152
#define HSTRIDE (BATCH * DHID)     // 16384
#define NT (BATCH * DHID)          // 16384 chains
#define NT4 (NT / 4)               // 4096 thread-chains (4 d each)

// pass1: per-(chain4, chunk) affine summary (A, B). Reads F,Z only (128 MB).
__global__ __launch_bounds__(256) void qrnn_scan_pass1(
    const unsigned short* __restrict__ Y,
    float* __restrict__ Aarr,            // (PCH, NT)
    float* __restrict__ Barr)            // (PCH, NT)
{
  const int g = blockIdx.x * 256 + threadIdx.x;  // 0..262143
  const int t = g & (NT4 - 1);       // 0..4095
  const int p = g >> 12;             // chunk 0..63
  const int b = t >> 8;              // batch
  const int d = (t & 255) << 2;      // d, multiple of 4
  const unsigned short* base =
      Y + (size_t)(p * LCH) * SSTRIDE + (size_t)b * N3 + d;

  float a[4] = {1.0f, 1.0f, 1.0f, 1.0f};
  float bv[4] = {0.0f, 0.0f, 0.0f, 0.0f};
  u16x4 z0[U], f0[U], z1[U], f1[U];

#define LOADZF(ch, zz, ff) { \
    const unsigned short* p_ = base + (size_t)(ch) * ((size_t)U * SSTRIDE); \
    _Pragma("unroll") \
    for (int j2 = 0; j2 < U; ++j2) { \
      zz[j2] = *(const u16x4*)(p_ + (size_t)j2 * SSTRIDE); \
      ff[j2] = *(const u16x4*)(p_ + (size_t)j2 * SSTRIDE + DHID); \
    } }

#define COMPAB(zz, ff) { \
    _Pragma("unroll") \
    for (int j2 = 0; j2 < U; ++j2) { \
      _Pragma("unroll") \
      for (int q = 0; q < 4; ++q) { \
        float zv = b2f(zz[j2][q]); \
        float fv = b2f(ff[j2][q]); \
        a[q]  = fmaf(-fv, a[q], a[q]);        /* a *= (1-f)          */ \
        bv[q] = fmaf(fv, zv - bv[q], bv[q]);  /* bv = f*z + (1-f)*bv */ \
      } \
    } }

  LOADZF(0, z0, f0);
  for (int ch = 0; ch < SUBCH; ch += 2) {
    LOADZF(ch + 1, z1, f1);
    COMPAB(z0, f0);
    if (ch + 2 < SUBCH) LOADZF(ch + 2, z0, f0);
    COMPAB(z1, f1);
  }
  ((float4*)Aarr)[g] = make_float4(a[0], a[1], a[2], a[3]);
  ((float4*)Barr)[g] = make_float4(bv[0], bv[1], bv[2], bv[3]);
}

// combine: sequential composition across the 64 chunk summaries per chain.
__global__ __launch_bounds__(256) void qrnn_combine(
    const float* __restrict__ Aarr,
    const float* __restrict__ Barr,
    const float* __restrict__ h0,        // (16,1024) fp32
    float* __restrict__ Cin,             // (PCH, NT)
    float* __restrict__ out)             // C_last at S*HSTRIDE + t
{
  const int t = blockIdx.x * 256 + threadIdx.x;  // 0..16383
  float c = h0[t];
#pragma unroll
  for (int p = 0; p < PCH; ++p) {
    Cin[p * NT + t] = c;
    c = fmaf(Aarr[p * NT + t], c, Barr[p * NT + t]);
  }
  out[(size_t)S_LEN * HSTRIDE + t] = c;  // C_last fp32
}

// pass2: exact per-step recurrence within each chunk from its entry state;
// h = o * c (o pre-activated by GEMM epilogue). Reads 196 MB, writes 128 MB.
__global__ __launch_bounds__(256) void qrnn_scan_pass2(
    const unsigned short* __restrict__ Y,
    const float* __restrict__ Cin,       // (PCH, NT)
    float* __restrict__ out)             // H (2048,16,1024) fp32
{
  const int g = blockIdx.x * 256 + threadIdx.x;  // 0..262143
  const int t = g & (NT4 - 1);
  const int p = g >> 12;
  const int b = t >> 8;
  const int d = (t & 255) << 2;
  const unsigned short* base =
      Y + (size_t)(p * LCH) * SSTRIDE + (size_t)b * N3 + d;
  float* ho = out + (size_t)(p * LCH) * HSTRIDE + (size_t)b * DHID + d;

  float4 cv = ((const float4*)Cin)[g];
  float c[4] = {cv.x, cv.y, cv.z, cv.w};

  u16x4 z0[U], f0[U], o0[U], z1[U], f1[U], o1[U];

#define LOADCH(ch, zz, ff, oo) { \
    const unsigned short* p_ = base + (size_t)(ch) * ((size_t)U * SSTRIDE); \
    _Pragma("unroll") \
    for (int j2 = 0; j2 < U; ++j2) { \
      zz[j2] = *(const u16x4*)(p_ + (size_t)j2 * SSTRIDE); \
      ff[j2] = *(const u16x4*)(p_ + (size_t)j2 * SSTRIDE + DHID); \
      oo[j2] = *(const u16x4*)(p_ + (size_t)j2 * SSTRIDE + 2 * DHID); \
    } }

#define COMPCH(ch, zz, ff, oo) { \
    float* q_ = ho + (size_t)(ch) * ((size_t)U * HSTRIDE); \
    _Pragma("unroll") \
    for (int j2 = 0; j2 < U; ++j2) { \
      float hv[4]; \
      _Pragma("unroll") \
      for (int q = 0; q < 4; ++q) { \
        float zv = b2f(zz[j2][q]); \
        float fv = b2f(ff[j2][q]); \
        float ov = b2f(oo[j2][q]); \
        c[q] = fmaf(fv, zv - c[q], c[q]); \
        hv[q] = ov * c[q]; \
      } \
      *(float4*)(q_ + (size_t)j2 * HSTRIDE) = \
          make_float4(hv[0], hv[1], hv[2], hv[3]); \
    } }

  LOADCH(0, z0, f0, o0);
  for (int ch = 0; ch < SUBCH; ch += 2) {
    LOADCH(ch + 1, z1, f1, o1);
    COMPCH(ch, z0, f0, o0);
    if (ch + 2 < SUBCH) LOADCH(ch + 2, z0, f0, o0);
    COMPCH(ch + 1, z1, f1, o1);
  }
}

// ---------------------------------------------------------------------------
extern "C" void kernel_launch(void* const* d_in, const int* in_sizes, int n_in,
                              void* d_out, int out_size, void* d_ws, size_t ws_size,
                              hipStream_t stream) {
  const float* X    = (const float*)d_in[0]; // (2048,16,1024) fp32
  const float* h0   = (const float*)d_in[1]; // (16,1024)      fp32
  const float* W    = (const float*)d_in[2]; // (3072,1024)    fp32
  const float* bias = (const float*)d_in[3]; // (3072)         fp32
  float* out = (float*)d_out;                // fp32 H ++ C_last (128.06 MiB)

  // ws: Y bf16 (192 MiB) ++ Wbf (6 MiB). Xbf (64 MiB) parks in d_out's H
  // region, consumed by the GEMM before pass2 rewrites it.
  // Aarr/Barr (4 MB each) live in the TAIL of the H region (last 8 MiB =
  // rows s>=1920): written by pass1, read by combine, then freely
  // overwritten by pass2's H stores (stream-ordered after combine).
  // Cin (4 MB) reuses the dead Wbf region (<= 6 MiB).
  unsigned short* Ybf = (unsigned short*)d_ws;
  unsigned short* Wbf = Ybf + YELEMS;
  unsigned short* Xbf = (unsigned short*)out;
  float* Aarr = out + ((size_t)S_LEN * HSTRIDE - 2 * (size_t)PCH * NT);
  float* Barr = Aarr + (size_t)PCH * NT;
  float* CinA = (float*)Wbf;
  static_assert((size_t)PCH * NT * 4 <= (size_t)WELEMS * 2,
                "Cin must fit in Wbf region");

  cvt_f32_bf16<<<(int)(XELEMS / 4 + 255) / 256, 256, 0, stream>>>(X, Xbf, (int)(XELEMS / 4));
  cvt_f32_bf16<<<(int)(WELEMS / 4 + 255) / 256, 256, 0, stream>>>(W, Wbf, (int)(WELEMS / 4));
  qrnn_gemm<<<dim3((MROWS / 256) * (N3 / 256)), 512, 0, stream>>>(Xbf, Wbf, bias, Ybf);
  qrnn_scan_pass1<<<dim3((PCH * NT4) / 256), 256, 0, stream>>>(Ybf, Aarr, Barr);
  qrnn_combine<<<dim3(NT / 256), 256, 0, stream>>>(Aarr, Barr, h0, CinA, out);
  qrnn_scan_pass2<<<dim3((PCH * NT4) / 256), 256, 0, stream>>>(Ybf, CinA, out);
}